// Round 1
// baseline (225.249 us; speedup 1.0000x reference)
//
#include <hip/hip_runtime.h>
#include <math.h>

// Cost weights / focal params (match reference)
#define W_CLASS 1.0f
#define W_BBOX  5.0f
#define W_GIOU  2.0f
#define F_ALPHA 0.25f
#define F_EPS   1e-8f

// Phase 1: per-row softmax over C=128 logits + focal class-cost table.
// delta[n*128 + c] = pos_cost(n,c) - neg_cost(n,c)
// One wave (64 lanes) per row, 4 rows per 256-thread block.
__global__ void class_cost_kernel(const float* __restrict__ logits,
                                  float* __restrict__ delta) {
    const int wave = threadIdx.x >> 6;
    const int lane = threadIdx.x & 63;
    const int n = blockIdx.x * 4 + wave;
    const float* row = logits + (size_t)n * 128;

    float x0 = row[lane];
    float x1 = row[lane + 64];

    // wave max-reduce
    float m = fmaxf(x0, x1);
    #pragma unroll
    for (int off = 32; off > 0; off >>= 1)
        m = fmaxf(m, __shfl_xor(m, off));

    float e0 = __expf(x0 - m);
    float e1 = __expf(x1 - m);
    float s = e0 + e1;
    #pragma unroll
    for (int off = 32; off > 0; off >>= 1)
        s += __shfl_xor(s, off);
    float inv = 1.0f / s;

    float p0 = e0 * inv;
    float p1 = e1 * inv;

    // focal: pos = a*(1-p)^2*(-log(p+eps)); neg = (1-a)*p^2*(-log(1-p+eps))
    float omp0 = 1.0f - p0;
    float d0 = F_ALPHA * omp0 * omp0 * (-logf(p0 + F_EPS))
             - (1.0f - F_ALPHA) * p0 * p0 * (-logf(1.0f - p0 + F_EPS));
    float omp1 = 1.0f - p1;
    float d1 = F_ALPHA * omp1 * omp1 * (-logf(p1 + F_EPS))
             - (1.0f - F_ALPHA) * p1 * p1 * (-logf(1.0f - p1 + F_EPS));

    delta[(size_t)n * 128 + lane]      = d0;
    delta[(size_t)n * 128 + lane + 64] = d1;
}

// Phase 2: full cost matrix. One thread per target t, ROWS_PER_BLOCK rows per
// block (reuses tgt loads). Output write is coalesced along t.
#define ROWS_PER_BLOCK 4

__global__ __launch_bounds__(256)
void cost_kernel(const float4* __restrict__ pred_boxes,   // [N,4] cxcywh
                 const float4* __restrict__ tgt_bbox,     // [T,4] cxcywh
                 const int* __restrict__ tgt_ids,         // [T]
                 const float* __restrict__ delta,         // [N,128]
                 float* __restrict__ out,                 // [N,T]
                 int T) {
    const int t = blockIdx.x * blockDim.x + threadIdx.x;
    const bool active = (t < T);
    const int tt = active ? t : 0;

    const float4 tb = tgt_bbox[tt];
    const int id = tgt_ids[tt];

    // tgt xyxy + area
    const float tx0 = tb.x - 0.5f * tb.z, ty0 = tb.y - 0.5f * tb.w;
    const float tx1 = tb.x + 0.5f * tb.z, ty1 = tb.y + 0.5f * tb.w;
    const float tarea = (tx1 - tx0) * (ty1 - ty0);

    const int n0 = blockIdx.y * ROWS_PER_BLOCK;

    #pragma unroll
    for (int r = 0; r < ROWS_PER_BLOCK; ++r) {
        const int n = n0 + r;
        const float4 pb = pred_boxes[n];   // uniform across block -> s_load
        const float px0 = pb.x - 0.5f * pb.z, py0 = pb.y - 0.5f * pb.w;
        const float px1 = pb.x + 0.5f * pb.z, py1 = pb.y + 0.5f * pb.w;
        const float parea = (px1 - px0) * (py1 - py0);

        const float d = delta[n * 128 + id];   // 4B gather within 512B row (L1)

        if (active) {
            // L1 cost on raw cxcywh
            float cb = fabsf(pb.x - tb.x) + fabsf(pb.y - tb.y)
                     + fabsf(pb.z - tb.z) + fabsf(pb.w - tb.w);

            // intersection
            float ix0 = fmaxf(px0, tx0), iy0 = fmaxf(py0, ty0);
            float ix1 = fminf(px1, tx1), iy1 = fminf(py1, ty1);
            float iw = fmaxf(ix1 - ix0, 0.0f), ih = fmaxf(iy1 - iy0, 0.0f);
            float inter = iw * ih;
            float uni = parea + tarea - inter;
            float iou = inter / uni;

            // enclosing box
            float ex0 = fminf(px0, tx0), ey0 = fminf(py0, ty0);
            float ex1 = fmaxf(px1, tx1), ey1 = fmaxf(py1, ty1);
            float earea = (ex1 - ex0) * (ey1 - ey0);
            float giou = iou - (earea - uni) / earea;

            out[(size_t)n * T + t] = W_BBOX * cb + W_CLASS * d - W_GIOU * giou;
        }
    }
}

extern "C" void kernel_launch(void* const* d_in, const int* in_sizes, int n_in,
                              void* d_out, int out_size, void* d_ws, size_t ws_size,
                              hipStream_t stream) {
    const float* pred_logits = (const float*)d_in[0];   // [16,900,128] f32
    const float* pred_boxes  = (const float*)d_in[1];   // [16,900,4]  f32
    const int*   tgt_ids     = (const int*)d_in[2];     // [3200] int32
    const float* tgt_bbox    = (const float*)d_in[3];   // [3200,4] f32
    float* out = (float*)d_out;
    float* delta = (float*)d_ws;                        // [14400,128] f32 = 7.4 MB

    const int N = in_sizes[1] / 4;   // bs*Q = 14400
    const int T = in_sizes[2];       // 3200

    // Phase 1: class-cost table (one wave per row, 4 rows/block)
    class_cost_kernel<<<N / 4, 256, 0, stream>>>(pred_logits, delta);

    // Phase 2: full cost matrix
    dim3 grid((T + 255) / 256, N / ROWS_PER_BLOCK);
    cost_kernel<<<grid, 256, 0, stream>>>(
        (const float4*)pred_boxes, (const float4*)tgt_bbox, tgt_ids, delta, out, T);
}